// Round 1
// baseline (4701.914 us; speedup 1.0000x reference)
//
#include <hip/hip_runtime.h>
#include <math.h>

#define BB 2
#define NN 8192
#define KK 16
#define DIMM 64
#define HH 32
#define NBB 5
#define RESS 64
#define NPTS (BB*NN)            // 16384
#define PLANE_ELEMS (BB*3*RESS*RESS*DIMM)   // 1572864
#define PLANE_CELLS (BB*3*RESS*RESS)        // 24576

// ---------------- zero workspace ----------------
__global__ void zero_kernel(float* __restrict__ p, int n) {
  int t = blockIdx.x * blockDim.x + threadIdx.x;
  if (t < n) p[t] = 0.0f;
}

// ---------------- stem: c = xyz @ w_stem + b_stem ; copy xyz to out ----------------
__global__ void stem_kernel(const float* __restrict__ xyz,
                            const float* __restrict__ w,
                            const float* __restrict__ bias,
                            float* __restrict__ out_xyz,
                            float* __restrict__ c) {
  int tid = blockIdx.x * blockDim.x + threadIdx.x;
  if (tid < NPTS*3) out_xyz[tid] = xyz[tid];
  if (tid < NPTS*DIMM) {
    int p = tid >> 6, d = tid & 63;
    float x = xyz[p*3+0], y = xyz[p*3+1], z = xyz[p*3+2];
    c[tid] = x*w[d] + y*w[64+d] + z*w[128+d] + bias[d];
  }
}

// ---------------- brute-force KNN, stable top-16 smallest d2 ----------------
#define CHUNK 2048
__global__ __launch_bounds__(256) void knn_kernel(const float* __restrict__ xyz,
                                                  int* __restrict__ idx) {
  __shared__ float4 cand[CHUNK];   // 32 KB
  int b = blockIdx.x >> 5;                         // 32 blocks per batch
  int q = ((blockIdx.x & 31) << 8) + threadIdx.x;  // query index in [0,N)
  const float* base = xyz + b*NN*3;
  float qx = base[q*3+0], qy = base[q*3+1], qz = base[q*3+2];
  float qs = qx*qx + qy*qy + qz*qz;
  float bd[16]; int bi[16];
#pragma unroll
  for (int j = 0; j < 16; ++j) { bd[j] = 3.0e38f; bi[j] = 0; }
  for (int ch = 0; ch < NN/CHUNK; ++ch) {
    __syncthreads();
    for (int t = threadIdx.x; t < CHUNK; t += 256) {
      int m = ch*CHUNK + t;
      float xx = base[m*3+0], yy = base[m*3+1], zz = base[m*3+2];
      cand[t] = make_float4(xx, yy, zz, xx*xx + yy*yy + zz*zz);
    }
    __syncthreads();
#pragma unroll 4
    for (int t = 0; t < CHUNK; ++t) {
      float4 c4 = cand[t];
      float d2 = (qs + c4.w) - 2.0f*(qx*c4.x + qy*c4.y + qz*c4.z);
      if (d2 < bd[15]) {           // strict: ties keep earlier (lower) index
        float cd = d2; int ci = ch*CHUNK + t;
#pragma unroll
        for (int j = 0; j < 16; ++j) {
          if (cd < bd[j]) { float td=bd[j]; int ti=bi[j]; bd[j]=cd; bi[j]=ci; cd=td; ci=ti; }
        }
      }
    }
  }
  int* op = idx + (b*NN + q)*16;
#pragma unroll
  for (int j = 0; j < 16; ++j) op[j] = bi[j];
}

// ---------------- x = relu(c @ w0[l] + b0[l]) ----------------
__global__ void xproj_kernel(const float* __restrict__ c,
                             const float* __restrict__ w0,
                             const float* __restrict__ b0,
                             float* __restrict__ x, int layer) {
  int tid = blockIdx.x * blockDim.x + threadIdx.x;
  if (tid >= NPTS*HH) return;
  int p = tid >> 5, h = tid & 31;
  const float* w = w0 + layer*DIMM*HH;
  const float* cr = c + p*DIMM;
  float acc = b0[layer*HH + h];
#pragma unroll
  for (int d = 0; d < DIMM; ++d) acc += cr[d]*w[d*HH + h];
  x[tid] = fmaxf(acc, 0.0f);
}

// ---------------- fused FKAConv + w2 + residual: one wave per point ----------------
__global__ __launch_bounds__(64) void conv_kernel(
    float* __restrict__ c, const float* __restrict__ x,
    const int* __restrict__ idx, const float* __restrict__ xyz,
    const float* __restrict__ fc1, const float* __restrict__ fc2,
    const float* __restrict__ fc3, const float* __restrict__ wcv,
    const float* __restrict__ alpha, const float* __restrict__ beta,
    const float* __restrict__ w2, const float* __restrict__ b2, int layer)
{
  int p = blockIdx.x;          // 0..NPTS-1, p = b*N + n
  int b = p >> 13;
  int tid = threadIdx.x;

  __shared__ float s_pts[16][3];
  __shared__ float s_dw[16];
  __shared__ float s_m1[16][16];
  __shared__ float s_m2[16][16];
  __shared__ float s_mm[16][16];
  __shared__ float s_mp[16];
  __shared__ float s_q[16];
  __shared__ float s_xn[16][32];
  __shared__ __align__(16) float s_f[512];
  __shared__ float s_y[32];
  __shared__ float s_w1[48];
  __shared__ float s_w2f[32][16];
  __shared__ float s_w3f[32][16];
  __shared__ int   s_idx[16];
  __shared__ float s_sum;

  const float* fc1l = fc1 + layer*3*KK;
  const float* fc2l = fc2 + layer*2*KK*KK;
  const float* fc3l = fc3 + layer*2*KK*KK;
  const float* wcvl = wcv + layer*HH*HH*KK;
  const float* w2l  = w2  + layer*HH*DIMM;
  const float* b2l  = b2  + layer*DIMM;

  if (tid < 16) s_idx[tid] = idx[p*16 + tid];
  if (tid < 48) s_w1[tid] = fc1l[tid];
#pragma unroll
  for (int r = 0; r < 8; ++r) {
    int e = tid + 64*r;
    ((float*)s_w2f)[e] = fc2l[e];
    ((float*)s_w3f)[e] = fc3l[e];
  }
  __syncthreads();

  float qx = xyz[p*3+0], qy = xyz[p*3+1], qz = xyz[p*3+2];
  if (tid < 16) {
    int j = s_idx[tid];
    const float* nb = xyz + (b*NN + j)*3;
    float px = nb[0]-qx, py = nb[1]-qy, pz = nb[2]-qz;
    s_pts[tid][0]=px; s_pts[tid][1]=py; s_pts[tid][2]=pz;
    float d = sqrtf(px*px + py*py + pz*pz + 1e-12f);
    s_dw[tid] = 1.0f/(1.0f + expf(alpha[layer]*d - beta[layer]));  // sigmoid(-a*d+b)
  }
  // gather neighbor features (overlaps with dw reduction path)
#pragma unroll
  for (int r = 0; r < 8; ++r) {
    int e = tid + 64*r;
    int k = e >> 5, cc = e & 31;
    s_xn[k][cc] = x[(b*NN + s_idx[k])*HH + cc];
  }
  __syncthreads();
  if (tid == 0) {
    float ssum = 0.0f;
#pragma unroll
    for (int k2 = 0; k2 < 16; ++k2) ssum += s_dw[k2];
    s_sum = ssum + 1e-6f;
  }
  __syncthreads();
  if (tid < 16) s_dw[tid] = s_dw[tid] / s_sum * 16.0f;
  __syncthreads();

  int ss = tid & 15;
  int kb = tid >> 4;
  // m1 = relu(pts @ fc1)
#pragma unroll
  for (int r = 0; r < 4; ++r) {
    int k = kb + 4*r;
    float v = s_pts[k][0]*s_w1[ss] + s_pts[k][1]*s_w1[16+ss] + s_pts[k][2]*s_w1[32+ss];
    s_m1[k][ss] = fmaxf(v, 0.0f);
  }
  __syncthreads();
  if (tid < 16) {                       // mp1[s] = max_k m1*dw
    float v = 0.0f;
#pragma unroll
    for (int k = 0; k < 16; ++k) v = fmaxf(v, s_m1[k][tid]*s_dw[k]);
    s_mp[tid] = v;
  }
  __syncthreads();
  if (tid < 16) {                       // q1[s] = mp1 @ fc2[16:,:]
    float qv = 0.0f;
#pragma unroll
    for (int t = 0; t < 16; ++t) qv += s_mp[t]*s_w2f[16+t][tid];
    s_q[tid] = qv;
  }
  __syncthreads();
  // m2 = relu(m1 @ fc2[:16,:] + q1)
#pragma unroll
  for (int r = 0; r < 4; ++r) {
    int k = kb + 4*r;
    float v = s_q[ss];
#pragma unroll
    for (int t = 0; t < 16; ++t) v += s_m1[k][t]*s_w2f[t][ss];
    s_m2[k][ss] = fmaxf(v, 0.0f);
  }
  __syncthreads();
  if (tid < 16) {                       // mp2
    float v = 0.0f;
#pragma unroll
    for (int k = 0; k < 16; ++k) v = fmaxf(v, s_m2[k][tid]*s_dw[k]);
    s_mp[tid] = v;
  }
  __syncthreads();
  if (tid < 16) {                       // q2
    float qv = 0.0f;
#pragma unroll
    for (int t = 0; t < 16; ++t) qv += s_mp[t]*s_w3f[16+t][tid];
    s_q[tid] = qv;
  }
  __syncthreads();
  // m3 = relu(m2 @ fc3[:16,:] + q2); mm = m3 * dw
#pragma unroll
  for (int r = 0; r < 4; ++r) {
    int k = kb + 4*r;
    float v = s_q[ss];
#pragma unroll
    for (int t = 0; t < 16; ++t) v += s_m2[k][t]*s_w3f[t][ss];
    s_mm[k][ss] = fmaxf(v, 0.0f) * s_dw[k];
  }
  __syncthreads();
  // f[c][s] = sum_k xn[k][c] * mm[k][s]
#pragma unroll
  for (int r = 0; r < 8; ++r) {
    int e = tid + 64*r;
    int fs = e & 15, fcc = e >> 4;
    float v = 0.0f;
#pragma unroll
    for (int k = 0; k < 16; ++k) v += s_xn[k][fcc]*s_mm[k][fs];
    s_f[fcc*16 + fs] = v;
  }
  __syncthreads();
  // y[o] = relu(sum_cs f[cs] * wcv[o][cs]) — 2 lanes per o, halves merged by shfl
  {
    int o = tid & 31, part = tid >> 5;
    const float4* wv = (const float4*)(wcvl + o*512 + part*256);
    const float4* fv = (const float4*)(s_f + part*256);
    float acc = 0.0f;
#pragma unroll
    for (int j = 0; j < 64; ++j) {
      float4 w4 = wv[j];
      float4 f4 = fv[j];
      acc += w4.x*f4.x; acc += w4.y*f4.y; acc += w4.z*f4.z; acc += w4.w*f4.w;
    }
    acc += __shfl_xor(acc, 32);
    if (tid < 32) s_y[tid] = fmaxf(acc, 0.0f);
  }
  __syncthreads();
  // c = relu(y @ w2 + b2 + c)
  {
    float zv = b2l[tid];
#pragma unroll
    for (int o = 0; o < 32; ++o) zv += s_y[o]*w2l[o*DIMM + tid];
    float cv = c[p*DIMM + tid];
    c[p*DIMM + tid] = fmaxf(zv + cv, 0.0f);
  }
}

// ---------------- triplane scatter-accumulate ----------------
__global__ void triacc_kernel(const float* __restrict__ c,
                              const float* __restrict__ xyz,
                              float* __restrict__ psum,
                              float* __restrict__ pcnt) {
  int tid = blockIdx.x * blockDim.x + threadIdx.x;
  if (tid >= NPTS*DIMM) return;
  int p = tid >> 6, d = tid & 63;
  int b = p >> 13;
  // pn = xyz/1.101 + 0.5 ; cell = clip(int(pn*64), 0, 63) — IEEE div matches ref bitwise
  float p0 = xyz[p*3+0] / 1.101f + 0.5f;
  float p1 = xyz[p*3+1] / 1.101f + 0.5f;
  float p2 = xyz[p*3+2] / 1.101f + 0.5f;
  int i0 = min(max((int)(p0*64.0f), 0), 63);
  int i1 = min(max((int)(p1*64.0f), 0), 63);
  int i2 = min(max((int)(p2*64.0f), 0), 63);
  int cb = b*3*RESS*RESS;
  int c0 = cb + 0*RESS*RESS + i0*RESS + i1;   // xy plane
  int c1 = cb + 1*RESS*RESS + i0*RESS + i2;   // xz plane
  int c2 = cb + 2*RESS*RESS + i1*RESS + i2;   // yz plane
  float v = c[tid];
  atomicAdd(&psum[c0*DIMM + d], v);
  atomicAdd(&psum[c1*DIMM + d], v);
  atomicAdd(&psum[c2*DIMM + d], v);
  if (d == 0) {
    atomicAdd(&pcnt[c0], 1.0f);
    atomicAdd(&pcnt[c1], 1.0f);
    atomicAdd(&pcnt[c2], 1.0f);
  }
}

// ---------------- triplane normalize ----------------
__global__ void trinorm_kernel(const float* __restrict__ psum,
                               const float* __restrict__ pcnt,
                               float* __restrict__ out) {
  int tid = blockIdx.x * blockDim.x + threadIdx.x;
  if (tid >= PLANE_ELEMS) return;
  float cnt = pcnt[tid >> 6];
  out[tid] = psum[tid] / fmaxf(cnt, 1.0f);
}

extern "C" void kernel_launch(void* const* d_in, const int* in_sizes, int n_in,
                              void* d_out, int out_size, void* d_ws, size_t ws_size,
                              hipStream_t stream) {
  const float* xyz   = (const float*)d_in[0];
  const float* wstem = (const float*)d_in[1];
  const float* bstem = (const float*)d_in[2];
  const float* w0    = (const float*)d_in[3];
  const float* b0    = (const float*)d_in[4];
  const float* fc1   = (const float*)d_in[5];
  const float* fc2   = (const float*)d_in[6];
  const float* fc3   = (const float*)d_in[7];
  const float* wcv   = (const float*)d_in[8];
  const float* alpha = (const float*)d_in[9];
  const float* beta  = (const float*)d_in[10];
  const float* w2    = (const float*)d_in[11];
  const float* b2    = (const float*)d_in[12];

  float* out     = (float*)d_out;
  float* out_xyz = out;                       // 49152
  float* c       = out + NPTS*3;              // 1048576 (used as working c buffer)
  float* out_tri = c + NPTS*DIMM;             // 1572864

  // workspace layout (floats): idx | x | psum | pcnt  (~9.3 MB total)
  float* wsf  = (float*)d_ws;
  int*   idx  = (int*)d_ws;                   // NPTS*16 int32
  float* x    = wsf + NPTS*16;                // NPTS*32
  float* psum = x + NPTS*HH;                  // PLANE_ELEMS
  float* pcnt = psum + PLANE_ELEMS;           // PLANE_CELLS

  int nz = PLANE_ELEMS + PLANE_CELLS;         // psum & pcnt contiguous
  zero_kernel<<<(nz+255)/256, 256, 0, stream>>>(psum, nz);
  stem_kernel<<<(NPTS*DIMM+255)/256, 256, 0, stream>>>(xyz, wstem, bstem, out_xyz, c);
  knn_kernel<<<64, 256, 0, stream>>>(xyz, idx);
  for (int layer = 0; layer < NBB; ++layer) {
    xproj_kernel<<<(NPTS*HH+255)/256, 256, 0, stream>>>(c, w0, b0, x, layer);
    conv_kernel<<<NPTS, 64, 0, stream>>>(c, x, idx, xyz, fc1, fc2, fc3, wcv,
                                         alpha, beta, w2, b2, layer);
  }
  triacc_kernel<<<(NPTS*DIMM+255)/256, 256, 0, stream>>>(c, xyz, psum, pcnt);
  trinorm_kernel<<<(PLANE_ELEMS+255)/256, 256, 0, stream>>>(psum, pcnt, out_tri);
}

// Round 2
// 2418.194 us; speedup vs baseline: 1.9444x; 1.9444x over previous
//
#include <hip/hip_runtime.h>
#include <math.h>

#define BB 2
#define NN 8192
#define KK 16
#define DIMM 64
#define HH 32
#define NBB 5
#define RESS 64
#define NPTS (BB*NN)            // 16384
#define PLANE_ELEMS (BB*3*RESS*RESS*DIMM)   // 1572864
#define PLANE_CELLS (BB*3*RESS*RESS)        // 24576

// ---------------- zero workspace ----------------
__global__ void zero_kernel(float* __restrict__ p, int n) {
  int t = blockIdx.x * blockDim.x + threadIdx.x;
  if (t < n) p[t] = 0.0f;
}

// ---------------- stem: c = xyz @ w_stem + b_stem ; copy xyz to out ----------------
__global__ void stem_kernel(const float* __restrict__ xyz,
                            const float* __restrict__ w,
                            const float* __restrict__ bias,
                            float* __restrict__ out_xyz,
                            float* __restrict__ c) {
  int tid = blockIdx.x * blockDim.x + threadIdx.x;
  if (tid < NPTS*3) out_xyz[tid] = xyz[tid];
  if (tid < NPTS*DIMM) {
    int p = tid >> 6, d = tid & 63;
    float x = xyz[p*3+0], y = xyz[p*3+1], z = xyz[p*3+2];
    c[tid] = x*w[d] + y*w[64+d] + z*w[128+d] + bias[d];
  }
}

// ---------------- brute-force KNN v2 ----------------
// 512 threads = 64 queries x 8 candidate slices; grid 256 (one block/CU).
// Stage 4096 candidates (64 KB) at a time; each slice-thread keeps a private
// sorted top-16 over its 1024 candidates; partials merged through LDS.
// d2 expression identical to v1 (which passed) for bitwise-stable selection.
__global__ __launch_bounds__(512) void knn_kernel(const float* __restrict__ xyz,
                                                  int* __restrict__ idx) {
  __shared__ __align__(16) float4 cand[4096];   // 64 KB; partials overlay after scans
  float* part_d = (float*)cand;                 // [128][64] floats (32 KB)
  int*   part_i = (int*)cand + 8192;            // [128][64] ints   (32 KB)

  int t = threadIdx.x;
  int s = t >> 6;                 // slice 0..7
  int ql = t & 63;                // query lane 0..63
  int b = blockIdx.x >> 7;        // batch
  int q = ((blockIdx.x & 127) << 6) + ql;   // query index in [0,N)
  const float* base = xyz + b*NN*3;

  float qx = base[q*3+0], qy = base[q*3+1], qz = base[q*3+2];
  float qs = qx*qx + qy*qy + qz*qz;

  float bd[16]; int bi[16];
#pragma unroll
  for (int j = 0; j < 16; ++j) { bd[j] = 3.0e38f; bi[j] = 0; }

  // two staging halves of 4096 candidates each
  for (int half = 0; half < 2; ++half) {
    __syncthreads();
    for (int i = t; i < 4096; i += 512) {
      int m = half*4096 + i;
      float xx = base[m*3+0], yy = base[m*3+1], zz = base[m*3+2];
      cand[i] = make_float4(xx, yy, zz, xx*xx + yy*yy + zz*zz);
    }
    __syncthreads();
    int lbase = s*512;
#pragma unroll 4
    for (int j = 0; j < 512; ++j) {
      float4 c4 = cand[lbase + j];
      float d2 = (qs + c4.w) - 2.0f*(qx*c4.x + qy*c4.y + qz*c4.z);
      if (d2 < bd[15]) {           // strict: ties keep earlier (lower) index
        float cd = d2; int ci = half*4096 + lbase + j;
#pragma unroll
        for (int jj = 0; jj < 16; ++jj) {
          if (cd < bd[jj]) { float td=bd[jj]; int ti=bi[jj]; bd[jj]=cd; bi[jj]=ci; cd=td; ci=ti; }
        }
      }
    }
  }
  __syncthreads();
  // write partials: row j = s*16 + rank, col = query lane (conflict-free)
#pragma unroll
  for (int j = 0; j < 16; ++j) {
    part_d[(s*16 + j)*64 + ql] = bd[j];
    part_i[(s*16 + j)*64 + ql] = bi[j];
  }
  __syncthreads();
  if (t < 64) {
    // merge 8 sorted slices in ascending-slice order (= ascending index ranges)
    float md[16]; int mi[16];
#pragma unroll
    for (int j = 0; j < 16; ++j) { md[j] = 3.0e38f; mi[j] = 0; }
    for (int j = 0; j < 128; ++j) {
      float cd = part_d[j*64 + t];
      if (cd < md[15]) {
        int ci = part_i[j*64 + t];
#pragma unroll
        for (int jj = 0; jj < 16; ++jj) {
          if (cd < md[jj]) { float td=md[jj]; int ti=mi[jj]; md[jj]=cd; mi[jj]=ci; cd=td; ci=ti; }
        }
      }
    }
    int* op = idx + (b*NN + q)*16;
#pragma unroll
    for (int j = 0; j < 16; ++j) op[j] = mi[j];
  }
}

// ---------------- x = relu(c @ w0[l] + b0[l]) ----------------
__global__ void xproj_kernel(const float* __restrict__ c,
                             const float* __restrict__ w0,
                             const float* __restrict__ b0,
                             float* __restrict__ x, int layer) {
  int tid = blockIdx.x * blockDim.x + threadIdx.x;
  if (tid >= NPTS*HH) return;
  int p = tid >> 5, h = tid & 31;
  const float* w = w0 + layer*DIMM*HH;
  const float* cr = c + p*DIMM;
  float acc = b0[layer*HH + h];
#pragma unroll
  for (int d = 0; d < DIMM; ++d) acc += cr[d]*w[d*HH + h];
  x[tid] = fmaxf(acc, 0.0f);
}

// ---------------- fused FKAConv + w2 + residual: one wave per point ----------------
__global__ __launch_bounds__(64) void conv_kernel(
    float* __restrict__ c, const float* __restrict__ x,
    const int* __restrict__ idx, const float* __restrict__ xyz,
    const float* __restrict__ fc1, const float* __restrict__ fc2,
    const float* __restrict__ fc3, const float* __restrict__ wcv,
    const float* __restrict__ alpha, const float* __restrict__ beta,
    const float* __restrict__ w2, const float* __restrict__ b2, int layer)
{
  int p = blockIdx.x;          // 0..NPTS-1, p = b*N + n
  int b = p >> 13;
  int tid = threadIdx.x;

  __shared__ float s_pts[16][3];
  __shared__ float s_dw[16];
  __shared__ float s_m1[16][16];
  __shared__ float s_m2[16][16];
  __shared__ float s_mm[16][16];
  __shared__ float s_mp[16];
  __shared__ float s_q[16];
  __shared__ float s_xn[16][32];
  __shared__ __align__(16) float s_f[512];
  __shared__ float s_y[32];
  __shared__ float s_w1[48];
  __shared__ float s_w2f[32][16];
  __shared__ float s_w3f[32][16];
  __shared__ int   s_idx[16];
  __shared__ float s_sum;

  const float* fc1l = fc1 + layer*3*KK;
  const float* fc2l = fc2 + layer*2*KK*KK;
  const float* fc3l = fc3 + layer*2*KK*KK;
  const float* wcvl = wcv + layer*HH*HH*KK;
  const float* w2l  = w2  + layer*HH*DIMM;
  const float* b2l  = b2  + layer*DIMM;

  if (tid < 16) s_idx[tid] = idx[p*16 + tid];
  if (tid < 48) s_w1[tid] = fc1l[tid];
#pragma unroll
  for (int r = 0; r < 8; ++r) {
    int e = tid + 64*r;
    ((float*)s_w2f)[e] = fc2l[e];
    ((float*)s_w3f)[e] = fc3l[e];
  }
  __syncthreads();

  float qx = xyz[p*3+0], qy = xyz[p*3+1], qz = xyz[p*3+2];
  if (tid < 16) {
    int j = s_idx[tid];
    const float* nb = xyz + (b*NN + j)*3;
    float px = nb[0]-qx, py = nb[1]-qy, pz = nb[2]-qz;
    s_pts[tid][0]=px; s_pts[tid][1]=py; s_pts[tid][2]=pz;
    float d = sqrtf(px*px + py*py + pz*pz + 1e-12f);
    s_dw[tid] = 1.0f/(1.0f + expf(alpha[layer]*d - beta[layer]));  // sigmoid(-a*d+b)
  }
  // gather neighbor features
#pragma unroll
  for (int r = 0; r < 8; ++r) {
    int e = tid + 64*r;
    int k = e >> 5, cc = e & 31;
    s_xn[k][cc] = x[(b*NN + s_idx[k])*HH + cc];
  }
  __syncthreads();
  if (tid == 0) {
    float ssum = 0.0f;
#pragma unroll
    for (int k2 = 0; k2 < 16; ++k2) ssum += s_dw[k2];
    s_sum = ssum + 1e-6f;
  }
  __syncthreads();
  if (tid < 16) s_dw[tid] = s_dw[tid] / s_sum * 16.0f;
  __syncthreads();

  int ss = tid & 15;
  int kb = tid >> 4;
  // m1 = relu(pts @ fc1)
#pragma unroll
  for (int r = 0; r < 4; ++r) {
    int k = kb + 4*r;
    float v = s_pts[k][0]*s_w1[ss] + s_pts[k][1]*s_w1[16+ss] + s_pts[k][2]*s_w1[32+ss];
    s_m1[k][ss] = fmaxf(v, 0.0f);
  }
  __syncthreads();
  if (tid < 16) {                       // mp1[s] = max_k m1*dw
    float v = 0.0f;
#pragma unroll
    for (int k = 0; k < 16; ++k) v = fmaxf(v, s_m1[k][tid]*s_dw[k]);
    s_mp[tid] = v;
  }
  __syncthreads();
  if (tid < 16) {                       // q1[s] = mp1 @ fc2[16:,:]
    float qv = 0.0f;
#pragma unroll
    for (int t = 0; t < 16; ++t) qv += s_mp[t]*s_w2f[16+t][tid];
    s_q[tid] = qv;
  }
  __syncthreads();
  // m2 = relu(m1 @ fc2[:16,:] + q1)
#pragma unroll
  for (int r = 0; r < 4; ++r) {
    int k = kb + 4*r;
    float v = s_q[ss];
#pragma unroll
    for (int t = 0; t < 16; ++t) v += s_m1[k][t]*s_w2f[t][ss];
    s_m2[k][ss] = fmaxf(v, 0.0f);
  }
  __syncthreads();
  if (tid < 16) {                       // mp2
    float v = 0.0f;
#pragma unroll
    for (int k = 0; k < 16; ++k) v = fmaxf(v, s_m2[k][tid]*s_dw[k]);
    s_mp[tid] = v;
  }
  __syncthreads();
  if (tid < 16) {                       // q2
    float qv = 0.0f;
#pragma unroll
    for (int t = 0; t < 16; ++t) qv += s_mp[t]*s_w3f[16+t][tid];
    s_q[tid] = qv;
  }
  __syncthreads();
  // m3 = relu(m2 @ fc3[:16,:] + q2); mm = m3 * dw
#pragma unroll
  for (int r = 0; r < 4; ++r) {
    int k = kb + 4*r;
    float v = s_q[ss];
#pragma unroll
    for (int t = 0; t < 16; ++t) v += s_m2[k][t]*s_w3f[t][ss];
    s_mm[k][ss] = fmaxf(v, 0.0f) * s_dw[k];
  }
  __syncthreads();
  // f[c][s] = sum_k xn[k][c] * mm[k][s]
#pragma unroll
  for (int r = 0; r < 8; ++r) {
    int e = tid + 64*r;
    int fs = e & 15, fcc = e >> 4;
    float v = 0.0f;
#pragma unroll
    for (int k = 0; k < 16; ++k) v += s_xn[k][fcc]*s_mm[k][fs];
    s_f[fcc*16 + fs] = v;
  }
  __syncthreads();
  // y[o] = relu(sum_cs f[cs] * wcv[o][cs]) — 2 lanes per o, halves merged by shfl
  {
    int o = tid & 31, part = tid >> 5;
    const float4* wv = (const float4*)(wcvl + o*512 + part*256);
    const float4* fv = (const float4*)(s_f + part*256);
    float acc = 0.0f;
#pragma unroll
    for (int j = 0; j < 64; ++j) {
      float4 w4 = wv[j];
      float4 f4 = fv[j];
      acc += w4.x*f4.x; acc += w4.y*f4.y; acc += w4.z*f4.z; acc += w4.w*f4.w;
    }
    acc += __shfl_xor(acc, 32);
    if (tid < 32) s_y[tid] = fmaxf(acc, 0.0f);
  }
  __syncthreads();
  // c = relu(y @ w2 + b2 + c)
  {
    float zv = b2l[tid];
#pragma unroll
    for (int o = 0; o < 32; ++o) zv += s_y[o]*w2l[o*DIMM + tid];
    float cv = c[p*DIMM + tid];
    c[p*DIMM + tid] = fmaxf(zv + cv, 0.0f);
  }
}

// ---------------- triplane scatter-accumulate ----------------
__global__ void triacc_kernel(const float* __restrict__ c,
                              const float* __restrict__ xyz,
                              float* __restrict__ psum,
                              float* __restrict__ pcnt) {
  int tid = blockIdx.x * blockDim.x + threadIdx.x;
  if (tid >= NPTS*DIMM) return;
  int p = tid >> 6, d = tid & 63;
  int b = p >> 13;
  float p0 = xyz[p*3+0] / 1.101f + 0.5f;
  float p1 = xyz[p*3+1] / 1.101f + 0.5f;
  float p2 = xyz[p*3+2] / 1.101f + 0.5f;
  int i0 = min(max((int)(p0*64.0f), 0), 63);
  int i1 = min(max((int)(p1*64.0f), 0), 63);
  int i2 = min(max((int)(p2*64.0f), 0), 63);
  int cb = b*3*RESS*RESS;
  int c0 = cb + 0*RESS*RESS + i0*RESS + i1;   // xy plane
  int c1 = cb + 1*RESS*RESS + i0*RESS + i2;   // xz plane
  int c2 = cb + 2*RESS*RESS + i1*RESS + i2;   // yz plane
  float v = c[tid];
  atomicAdd(&psum[c0*DIMM + d], v);
  atomicAdd(&psum[c1*DIMM + d], v);
  atomicAdd(&psum[c2*DIMM + d], v);
  if (d == 0) {
    atomicAdd(&pcnt[c0], 1.0f);
    atomicAdd(&pcnt[c1], 1.0f);
    atomicAdd(&pcnt[c2], 1.0f);
  }
}

// ---------------- triplane normalize ----------------
__global__ void trinorm_kernel(const float* __restrict__ psum,
                               const float* __restrict__ pcnt,
                               float* __restrict__ out) {
  int tid = blockIdx.x * blockDim.x + threadIdx.x;
  if (tid >= PLANE_ELEMS) return;
  float cnt = pcnt[tid >> 6];
  out[tid] = psum[tid] / fmaxf(cnt, 1.0f);
}

extern "C" void kernel_launch(void* const* d_in, const int* in_sizes, int n_in,
                              void* d_out, int out_size, void* d_ws, size_t ws_size,
                              hipStream_t stream) {
  const float* xyz   = (const float*)d_in[0];
  const float* wstem = (const float*)d_in[1];
  const float* bstem = (const float*)d_in[2];
  const float* w0    = (const float*)d_in[3];
  const float* b0    = (const float*)d_in[4];
  const float* fc1   = (const float*)d_in[5];
  const float* fc2   = (const float*)d_in[6];
  const float* fc3   = (const float*)d_in[7];
  const float* wcv   = (const float*)d_in[8];
  const float* alpha = (const float*)d_in[9];
  const float* beta  = (const float*)d_in[10];
  const float* w2    = (const float*)d_in[11];
  const float* b2    = (const float*)d_in[12];

  float* out     = (float*)d_out;
  float* out_xyz = out;                       // 49152
  float* c       = out + NPTS*3;              // 1048576 (used as working c buffer)
  float* out_tri = c + NPTS*DIMM;             // 1572864

  // workspace layout (floats): idx | x | psum | pcnt  (~9.3 MB total)
  float* wsf  = (float*)d_ws;
  int*   idx  = (int*)d_ws;                   // NPTS*16 int32
  float* x    = wsf + NPTS*16;                // NPTS*32
  float* psum = x + NPTS*HH;                  // PLANE_ELEMS
  float* pcnt = psum + PLANE_ELEMS;           // PLANE_CELLS

  int nz = PLANE_ELEMS + PLANE_CELLS;         // psum & pcnt contiguous
  zero_kernel<<<(nz+255)/256, 256, 0, stream>>>(psum, nz);
  stem_kernel<<<(NPTS*DIMM+255)/256, 256, 0, stream>>>(xyz, wstem, bstem, out_xyz, c);
  knn_kernel<<<256, 512, 0, stream>>>(xyz, idx);
  for (int layer = 0; layer < NBB; ++layer) {
    xproj_kernel<<<(NPTS*HH+255)/256, 256, 0, stream>>>(c, w0, b0, x, layer);
    conv_kernel<<<NPTS, 64, 0, stream>>>(c, x, idx, xyz, fc1, fc2, fc3, wcv,
                                         alpha, beta, w2, b2, layer);
  }
  triacc_kernel<<<(NPTS*DIMM+255)/256, 256, 0, stream>>>(c, xyz, psum, pcnt);
  trinorm_kernel<<<(PLANE_ELEMS+255)/256, 256, 0, stream>>>(psum, pcnt, out_tri);
}

// Round 3
// 1101.694 us; speedup vs baseline: 4.2679x; 2.1950x over previous
//
#include <hip/hip_runtime.h>
#include <math.h>

#define BB 2
#define NN 8192
#define KK 16
#define DIMM 64
#define HH 32
#define NBB 5
#define RESS 64
#define NPTS (BB*NN)            // 16384
#define PLANE_ELEMS (BB*3*RESS*RESS*DIMM)   // 1572864
#define PLANE_CELLS (BB*3*RESS*RESS)        // 24576
#define FINF 3.0e38f

// ---------------- zero workspace ----------------
__global__ void zero_kernel(float* __restrict__ p, int n) {
  int t = blockIdx.x * blockDim.x + threadIdx.x;
  if (t < n) p[t] = 0.0f;
}

// ---------------- stem: c = xyz @ w_stem + b_stem ; copy xyz to out ----------------
__global__ void stem_kernel(const float* __restrict__ xyz,
                            const float* __restrict__ w,
                            const float* __restrict__ bias,
                            float* __restrict__ out_xyz,
                            float* __restrict__ c) {
  int tid = blockIdx.x * blockDim.x + threadIdx.x;
  if (tid < NPTS*3) out_xyz[tid] = xyz[tid];
  if (tid < NPTS*DIMM) {
    int p = tid >> 6, d = tid & 63;
    float x = xyz[p*3+0], y = xyz[p*3+1], z = xyz[p*3+2];
    c[tid] = x*w[d] + y*w[64+d] + z*w[128+d] + bias[d];
  }
}

// ---------------- brute-force KNN v3 ----------------
// 512 threads = 64 queries x 8 candidate slices; grid 256.
// Inner loop: threshold check -> 4-deep register FIFO push (cheap) -> batched
// drain via PARALLEL branchless insert (no serial chain; INF item = no-op).
// Ties: pushes in ascending index order, FIFO drained in order, strict < keeps
// earlier index; slices merged in ascending index-range order. d2 expression
// identical to v1/v2 (bitwise-stable selection).
__global__ __launch_bounds__(512) void knn_kernel(const float* __restrict__ xyz,
                                                  int* __restrict__ idx) {
  __shared__ __align__(16) float4 cand[4096];   // 64 KB; partials overlay after scans
  float* part_d = (float*)cand;                 // [128][64] floats (32 KB)
  int*   part_i = (int*)cand + 8192;            // [128][64] ints   (32 KB)

  int t = threadIdx.x;
  int s = t >> 6;                 // slice 0..7
  int ql = t & 63;                // query lane 0..63
  int b = blockIdx.x >> 7;        // batch
  int q = ((blockIdx.x & 127) << 6) + ql;   // query index in [0,N)
  const float* base = xyz + b*NN*3;

  float qx = base[q*3+0], qy = base[q*3+1], qz = base[q*3+2];
  float qs = qx*qx + qy*qy + qz*qz;

  float bd[16]; int bi[16];
#pragma unroll
  for (int j = 0; j < 16; ++j) { bd[j] = FINF; bi[j] = 0; }

  float fd[4]; int fi[4]; int fcnt = 0;
#pragma unroll
  for (int j = 0; j < 4; ++j) { fd[j] = FINF; fi[j] = 0; }

  // parallel branchless insert into sorted bd/bi; cd==FINF is a no-op.
  // Descending in-place: slot jj reads OLD bd[jj-1], bd[jj] only -> no chain.
#define INSERT1(cd, ci)                                                        \
  {                                                                            \
    float _cd = (cd); int _ci = (ci);                                          \
    _Pragma("unroll")                                                          \
    for (int jj = 15; jj >= 1; --jj) {                                         \
      float up = bd[jj-1]; int ui = bi[jj-1];                                  \
      bool shift = _cd < up;                                                   \
      bool here  = _cd < bd[jj];                                               \
      float nv = shift ? up : _cd;                                             \
      int   ni = shift ? ui : _ci;                                             \
      bd[jj] = here ? nv : bd[jj];                                             \
      bi[jj] = here ? ni : bi[jj];                                             \
    }                                                                          \
    bool h0 = _cd < bd[0];                                                     \
    bd[0] = h0 ? _cd : bd[0];                                                  \
    bi[0] = h0 ? _ci : bi[0];                                                  \
  }

#define DRAIN()                                                                \
  {                                                                            \
    _Pragma("unroll")                                                          \
    for (int j2 = 0; j2 < 4; ++j2) {                                           \
      float _dd = (j2 < fcnt) ? fd[j2] : FINF;                                 \
      int   _di = (j2 < fcnt) ? fi[j2] : 0;                                    \
      INSERT1(_dd, _di);                                                       \
    }                                                                          \
    fcnt = 0;                                                                  \
  }

  // two staging halves of 4096 candidates each
  for (int half = 0; half < 2; ++half) {
    __syncthreads();
    for (int i = t; i < 4096; i += 512) {
      int m = half*4096 + i;
      float xx = base[m*3+0], yy = base[m*3+1], zz = base[m*3+2];
      cand[i] = make_float4(xx, yy, zz, xx*xx + yy*yy + zz*zz);
    }
    __syncthreads();
    int lbase = s*512;
#pragma unroll 4
    for (int j = 0; j < 512; ++j) {
      float4 c4 = cand[lbase + j];
      float d2 = (qs + c4.w) - 2.0f*(qx*c4.x + qy*c4.y + qz*c4.z);
      if (d2 < bd[15]) {     // threshold (stale between drains: only looser, safe)
        int ci = half*4096 + lbase + j;
#pragma unroll
        for (int j2 = 0; j2 < 4; ++j2) {
          fd[j2] = (fcnt == j2) ? d2 : fd[j2];
          fi[j2] = (fcnt == j2) ? ci : fi[j2];
        }
        fcnt++;
      }
      if (__any(fcnt >= 4)) { DRAIN(); }
    }
  }
  DRAIN();                   // flush remaining FIFO items
  __syncthreads();
  // write partials: row j = s*16 + rank, col = query lane (conflict-free)
#pragma unroll
  for (int j = 0; j < 16; ++j) {
    part_d[(s*16 + j)*64 + ql] = bd[j];
    part_i[(s*16 + j)*64 + ql] = bi[j];
  }
  __syncthreads();
  if (t < 64) {
    // merge 8 sorted slices in ascending-slice order (= ascending index ranges)
    float md[16]; int mi[16];
#pragma unroll
    for (int j = 0; j < 16; ++j) { md[j] = FINF; mi[j] = 0; }
    for (int j = 0; j < 128; ++j) {
      float cd = part_d[j*64 + t];
      if (cd < md[15]) {
        int ci = part_i[j*64 + t];
#pragma unroll
        for (int jj = 0; jj < 16; ++jj) {
          if (cd < md[jj]) { float td=md[jj]; int ti=mi[jj]; md[jj]=cd; mi[jj]=ci; cd=td; ci=ti; }
        }
      }
    }
    int* op = idx + (b*NN + q)*16;
#pragma unroll
    for (int j = 0; j < 16; ++j) op[j] = mi[j];
  }
}

// ---------------- x = relu(c @ w0[l] + b0[l]) ----------------
__global__ void xproj_kernel(const float* __restrict__ c,
                             const float* __restrict__ w0,
                             const float* __restrict__ b0,
                             float* __restrict__ x, int layer) {
  int tid = blockIdx.x * blockDim.x + threadIdx.x;
  if (tid >= NPTS*HH) return;
  int p = tid >> 5, h = tid & 31;
  const float* w = w0 + layer*DIMM*HH;
  const float* cr = c + p*DIMM;
  float acc = b0[layer*HH + h];
#pragma unroll
  for (int d = 0; d < DIMM; ++d) acc += cr[d]*w[d*HH + h];
  x[tid] = fmaxf(acc, 0.0f);
}

// ---------------- fused FKAConv + w2 + residual: one wave per point ----------------
__global__ __launch_bounds__(64) void conv_kernel(
    float* __restrict__ c, const float* __restrict__ x,
    const int* __restrict__ idx, const float* __restrict__ xyz,
    const float* __restrict__ fc1, const float* __restrict__ fc2,
    const float* __restrict__ fc3, const float* __restrict__ wcv,
    const float* __restrict__ alpha, const float* __restrict__ beta,
    const float* __restrict__ w2, const float* __restrict__ b2, int layer)
{
  int p = blockIdx.x;          // 0..NPTS-1, p = b*N + n
  int b = p >> 13;
  int tid = threadIdx.x;

  __shared__ float s_pts[16][3];
  __shared__ float s_dw[16];
  __shared__ float s_m1[16][16];
  __shared__ float s_m2[16][16];
  __shared__ float s_mm[16][16];
  __shared__ float s_mp[16];
  __shared__ float s_q[16];
  __shared__ float s_xn[16][32];
  __shared__ __align__(16) float s_f[512];
  __shared__ float s_y[32];
  __shared__ float s_w1[48];
  __shared__ float s_w2f[32][16];
  __shared__ float s_w3f[32][16];
  __shared__ int   s_idx[16];
  __shared__ float s_sum;

  const float* fc1l = fc1 + layer*3*KK;
  const float* fc2l = fc2 + layer*2*KK*KK;
  const float* fc3l = fc3 + layer*2*KK*KK;
  const float* wcvl = wcv + layer*HH*HH*KK;
  const float* w2l  = w2  + layer*HH*DIMM;
  const float* b2l  = b2  + layer*DIMM;

  if (tid < 16) s_idx[tid] = idx[p*16 + tid];
  if (tid < 48) s_w1[tid] = fc1l[tid];
#pragma unroll
  for (int r = 0; r < 8; ++r) {
    int e = tid + 64*r;
    ((float*)s_w2f)[e] = fc2l[e];
    ((float*)s_w3f)[e] = fc3l[e];
  }
  __syncthreads();

  float qx = xyz[p*3+0], qy = xyz[p*3+1], qz = xyz[p*3+2];
  if (tid < 16) {
    int j = s_idx[tid];
    const float* nb = xyz + (b*NN + j)*3;
    float px = nb[0]-qx, py = nb[1]-qy, pz = nb[2]-qz;
    s_pts[tid][0]=px; s_pts[tid][1]=py; s_pts[tid][2]=pz;
    float d = sqrtf(px*px + py*py + pz*pz + 1e-12f);
    s_dw[tid] = 1.0f/(1.0f + expf(alpha[layer]*d - beta[layer]));  // sigmoid(-a*d+b)
  }
  // gather neighbor features
#pragma unroll
  for (int r = 0; r < 8; ++r) {
    int e = tid + 64*r;
    int k = e >> 5, cc = e & 31;
    s_xn[k][cc] = x[(b*NN + s_idx[k])*HH + cc];
  }
  __syncthreads();
  if (tid == 0) {
    float ssum = 0.0f;
#pragma unroll
    for (int k2 = 0; k2 < 16; ++k2) ssum += s_dw[k2];
    s_sum = ssum + 1e-6f;
  }
  __syncthreads();
  if (tid < 16) s_dw[tid] = s_dw[tid] / s_sum * 16.0f;
  __syncthreads();

  int ss = tid & 15;
  int kb = tid >> 4;
  // m1 = relu(pts @ fc1)
#pragma unroll
  for (int r = 0; r < 4; ++r) {
    int k = kb + 4*r;
    float v = s_pts[k][0]*s_w1[ss] + s_pts[k][1]*s_w1[16+ss] + s_pts[k][2]*s_w1[32+ss];
    s_m1[k][ss] = fmaxf(v, 0.0f);
  }
  __syncthreads();
  if (tid < 16) {                       // mp1[s] = max_k m1*dw
    float v = 0.0f;
#pragma unroll
    for (int k = 0; k < 16; ++k) v = fmaxf(v, s_m1[k][tid]*s_dw[k]);
    s_mp[tid] = v;
  }
  __syncthreads();
  if (tid < 16) {                       // q1[s] = mp1 @ fc2[16:,:]
    float qv = 0.0f;
#pragma unroll
    for (int t = 0; t < 16; ++t) qv += s_mp[t]*s_w2f[16+t][tid];
    s_q[tid] = qv;
  }
  __syncthreads();
  // m2 = relu(m1 @ fc2[:16,:] + q1)
#pragma unroll
  for (int r = 0; r < 4; ++r) {
    int k = kb + 4*r;
    float v = s_q[ss];
#pragma unroll
    for (int t = 0; t < 16; ++t) v += s_m1[k][t]*s_w2f[t][ss];
    s_m2[k][ss] = fmaxf(v, 0.0f);
  }
  __syncthreads();
  if (tid < 16) {                       // mp2
    float v = 0.0f;
#pragma unroll
    for (int k = 0; k < 16; ++k) v = fmaxf(v, s_m2[k][tid]*s_dw[k]);
    s_mp[tid] = v;
  }
  __syncthreads();
  if (tid < 16) {                       // q2
    float qv = 0.0f;
#pragma unroll
    for (int t = 0; t < 16; ++t) qv += s_mp[t]*s_w3f[16+t][tid];
    s_q[tid] = qv;
  }
  __syncthreads();
  // m3 = relu(m2 @ fc3[:16,:] + q2); mm = m3 * dw
#pragma unroll
  for (int r = 0; r < 4; ++r) {
    int k = kb + 4*r;
    float v = s_q[ss];
#pragma unroll
    for (int t = 0; t < 16; ++t) v += s_m2[k][t]*s_w3f[t][ss];
    s_mm[k][ss] = fmaxf(v, 0.0f) * s_dw[k];
  }
  __syncthreads();
  // f[c][s] = sum_k xn[k][c] * mm[k][s]
#pragma unroll
  for (int r = 0; r < 8; ++r) {
    int e = tid + 64*r;
    int fs = e & 15, fcc = e >> 4;
    float v = 0.0f;
#pragma unroll
    for (int k = 0; k < 16; ++k) v += s_xn[k][fcc]*s_mm[k][fs];
    s_f[fcc*16 + fs] = v;
  }
  __syncthreads();
  // y[o] = relu(sum_cs f[cs] * wcv[o][cs]) — 2 lanes per o, halves merged by shfl
  {
    int o = tid & 31, part = tid >> 5;
    const float4* wv = (const float4*)(wcvl + o*512 + part*256);
    const float4* fv = (const float4*)(s_f + part*256);
    float acc = 0.0f;
#pragma unroll
    for (int j = 0; j < 64; ++j) {
      float4 w4 = wv[j];
      float4 f4 = fv[j];
      acc += w4.x*f4.x; acc += w4.y*f4.y; acc += w4.z*f4.z; acc += w4.w*f4.w;
    }
    acc += __shfl_xor(acc, 32);
    if (tid < 32) s_y[tid] = fmaxf(acc, 0.0f);
  }
  __syncthreads();
  // c = relu(y @ w2 + b2 + c)
  {
    float zv = b2l[tid];
#pragma unroll
    for (int o = 0; o < 32; ++o) zv += s_y[o]*w2l[o*DIMM + tid];
    float cv = c[p*DIMM + tid];
    c[p*DIMM + tid] = fmaxf(zv + cv, 0.0f);
  }
}

// ---------------- triplane scatter-accumulate ----------------
__global__ void triacc_kernel(const float* __restrict__ c,
                              const float* __restrict__ xyz,
                              float* __restrict__ psum,
                              float* __restrict__ pcnt) {
  int tid = blockIdx.x * blockDim.x + threadIdx.x;
  if (tid >= NPTS*DIMM) return;
  int p = tid >> 6, d = tid & 63;
  int b = p >> 13;
  float p0 = xyz[p*3+0] / 1.101f + 0.5f;
  float p1 = xyz[p*3+1] / 1.101f + 0.5f;
  float p2 = xyz[p*3+2] / 1.101f + 0.5f;
  int i0 = min(max((int)(p0*64.0f), 0), 63);
  int i1 = min(max((int)(p1*64.0f), 0), 63);
  int i2 = min(max((int)(p2*64.0f), 0), 63);
  int cb = b*3*RESS*RESS;
  int c0 = cb + 0*RESS*RESS + i0*RESS + i1;   // xy plane
  int c1 = cb + 1*RESS*RESS + i0*RESS + i2;   // xz plane
  int c2 = cb + 2*RESS*RESS + i1*RESS + i2;   // yz plane
  float v = c[tid];
  atomicAdd(&psum[c0*DIMM + d], v);
  atomicAdd(&psum[c1*DIMM + d], v);
  atomicAdd(&psum[c2*DIMM + d], v);
  if (d == 0) {
    atomicAdd(&pcnt[c0], 1.0f);
    atomicAdd(&pcnt[c1], 1.0f);
    atomicAdd(&pcnt[c2], 1.0f);
  }
}

// ---------------- triplane normalize ----------------
__global__ void trinorm_kernel(const float* __restrict__ psum,
                               const float* __restrict__ pcnt,
                               float* __restrict__ out) {
  int tid = blockIdx.x * blockDim.x + threadIdx.x;
  if (tid >= PLANE_ELEMS) return;
  float cnt = pcnt[tid >> 6];
  out[tid] = psum[tid] / fmaxf(cnt, 1.0f);
}

extern "C" void kernel_launch(void* const* d_in, const int* in_sizes, int n_in,
                              void* d_out, int out_size, void* d_ws, size_t ws_size,
                              hipStream_t stream) {
  const float* xyz   = (const float*)d_in[0];
  const float* wstem = (const float*)d_in[1];
  const float* bstem = (const float*)d_in[2];
  const float* w0    = (const float*)d_in[3];
  const float* b0    = (const float*)d_in[4];
  const float* fc1   = (const float*)d_in[5];
  const float* fc2   = (const float*)d_in[6];
  const float* fc3   = (const float*)d_in[7];
  const float* wcv   = (const float*)d_in[8];
  const float* alpha = (const float*)d_in[9];
  const float* beta  = (const float*)d_in[10];
  const float* w2    = (const float*)d_in[11];
  const float* b2    = (const float*)d_in[12];

  float* out     = (float*)d_out;
  float* out_xyz = out;                       // 49152
  float* c       = out + NPTS*3;              // 1048576 (used as working c buffer)
  float* out_tri = c + NPTS*DIMM;             // 1572864

  // workspace layout (floats): idx | x | psum | pcnt  (~9.3 MB total)
  float* wsf  = (float*)d_ws;
  int*   idx  = (int*)d_ws;                   // NPTS*16 int32
  float* x    = wsf + NPTS*16;                // NPTS*32
  float* psum = x + NPTS*HH;                  // PLANE_ELEMS
  float* pcnt = psum + PLANE_ELEMS;           // PLANE_CELLS

  int nz = PLANE_ELEMS + PLANE_CELLS;         // psum & pcnt contiguous
  zero_kernel<<<(nz+255)/256, 256, 0, stream>>>(psum, nz);
  stem_kernel<<<(NPTS*DIMM+255)/256, 256, 0, stream>>>(xyz, wstem, bstem, out_xyz, c);
  knn_kernel<<<256, 512, 0, stream>>>(xyz, idx);
  for (int layer = 0; layer < NBB; ++layer) {
    xproj_kernel<<<(NPTS*HH+255)/256, 256, 0, stream>>>(c, w0, b0, x, layer);
    conv_kernel<<<NPTS, 64, 0, stream>>>(c, x, idx, xyz, fc1, fc2, fc3, wcv,
                                         alpha, beta, w2, b2, layer);
  }
  triacc_kernel<<<(NPTS*DIMM+255)/256, 256, 0, stream>>>(c, xyz, psum, pcnt);
  trinorm_kernel<<<(PLANE_ELEMS+255)/256, 256, 0, stream>>>(psum, pcnt, out_tri);
}

// Round 4
// 715.588 us; speedup vs baseline: 6.5707x; 1.5396x over previous
//
#include <hip/hip_runtime.h>
#include <math.h>

#define BB 2
#define NN 8192
#define KK 16
#define DIMM 64
#define HH 32
#define NBB 5
#define RESS 64
#define NPTS (BB*NN)            // 16384
#define PLANE_ELEMS (BB*3*RESS*RESS*DIMM)   // 1572864
#define PLANE_CELLS (BB*3*RESS*RESS)        // 24576
#define FINF 3.0e38f

// ---------------- zero workspace ----------------
__global__ void zero_kernel(float* __restrict__ p, int n) {
  int t = blockIdx.x * blockDim.x + threadIdx.x;
  if (t < n) p[t] = 0.0f;
}

// ---------------- stem: c = xyz @ w_stem + b_stem ; copy xyz to out ----------------
__global__ void stem_kernel(const float* __restrict__ xyz,
                            const float* __restrict__ w,
                            const float* __restrict__ bias,
                            float* __restrict__ out_xyz,
                            float* __restrict__ c) {
  int tid = blockIdx.x * blockDim.x + threadIdx.x;
  if (tid < NPTS*3) out_xyz[tid] = xyz[tid];
  if (tid < NPTS*DIMM) {
    int p = tid >> 6, d = tid & 63;
    float x = xyz[p*3+0], y = xyz[p*3+1], z = xyz[p*3+2];
    c[tid] = x*w[d] + y*w[64+d] + z*w[128+d] + bias[d];
  }
}

// ---------------- brute-force KNN v3 (unchanged from R3) ----------------
__global__ __launch_bounds__(512) void knn_kernel(const float* __restrict__ xyz,
                                                  int* __restrict__ idx) {
  __shared__ __align__(16) float4 cand[4096];   // 64 KB; partials overlay after scans
  float* part_d = (float*)cand;                 // [128][64] floats (32 KB)
  int*   part_i = (int*)cand + 8192;            // [128][64] ints   (32 KB)

  int t = threadIdx.x;
  int s = t >> 6;                 // slice 0..7
  int ql = t & 63;                // query lane 0..63
  int b = blockIdx.x >> 7;        // batch
  int q = ((blockIdx.x & 127) << 6) + ql;   // query index in [0,N)
  const float* base = xyz + b*NN*3;

  float qx = base[q*3+0], qy = base[q*3+1], qz = base[q*3+2];
  float qs = qx*qx + qy*qy + qz*qz;

  float bd[16]; int bi[16];
#pragma unroll
  for (int j = 0; j < 16; ++j) { bd[j] = FINF; bi[j] = 0; }

  float fd[4]; int fi[4]; int fcnt = 0;
#pragma unroll
  for (int j = 0; j < 4; ++j) { fd[j] = FINF; fi[j] = 0; }

#define INSERT1(cd, ci)                                                        \
  {                                                                            \
    float _cd = (cd); int _ci = (ci);                                          \
    _Pragma("unroll")                                                          \
    for (int jj = 15; jj >= 1; --jj) {                                         \
      float up = bd[jj-1]; int ui = bi[jj-1];                                  \
      bool shift = _cd < up;                                                   \
      bool here  = _cd < bd[jj];                                               \
      float nv = shift ? up : _cd;                                             \
      int   ni = shift ? ui : _ci;                                             \
      bd[jj] = here ? nv : bd[jj];                                             \
      bi[jj] = here ? ni : bi[jj];                                             \
    }                                                                          \
    bool h0 = _cd < bd[0];                                                     \
    bd[0] = h0 ? _cd : bd[0];                                                  \
    bi[0] = h0 ? _ci : bi[0];                                                  \
  }

#define DRAIN()                                                                \
  {                                                                            \
    _Pragma("unroll")                                                          \
    for (int j2 = 0; j2 < 4; ++j2) {                                           \
      float _dd = (j2 < fcnt) ? fd[j2] : FINF;                                 \
      int   _di = (j2 < fcnt) ? fi[j2] : 0;                                    \
      INSERT1(_dd, _di);                                                       \
    }                                                                          \
    fcnt = 0;                                                                  \
  }

  for (int half = 0; half < 2; ++half) {
    __syncthreads();
    for (int i = t; i < 4096; i += 512) {
      int m = half*4096 + i;
      float xx = base[m*3+0], yy = base[m*3+1], zz = base[m*3+2];
      cand[i] = make_float4(xx, yy, zz, xx*xx + yy*yy + zz*zz);
    }
    __syncthreads();
    int lbase = s*512;
#pragma unroll 4
    for (int j = 0; j < 512; ++j) {
      float4 c4 = cand[lbase + j];
      float d2 = (qs + c4.w) - 2.0f*(qx*c4.x + qy*c4.y + qz*c4.z);
      if (d2 < bd[15]) {
        int ci = half*4096 + lbase + j;
#pragma unroll
        for (int j2 = 0; j2 < 4; ++j2) {
          fd[j2] = (fcnt == j2) ? d2 : fd[j2];
          fi[j2] = (fcnt == j2) ? ci : fi[j2];
        }
        fcnt++;
      }
      if (__any(fcnt >= 4)) { DRAIN(); }
    }
  }
  DRAIN();
  __syncthreads();
#pragma unroll
  for (int j = 0; j < 16; ++j) {
    part_d[(s*16 + j)*64 + ql] = bd[j];
    part_i[(s*16 + j)*64 + ql] = bi[j];
  }
  __syncthreads();
  if (t < 64) {
    float md[16]; int mi[16];
#pragma unroll
    for (int j = 0; j < 16; ++j) { md[j] = FINF; mi[j] = 0; }
    for (int j = 0; j < 128; ++j) {
      float cd = part_d[j*64 + t];
      if (cd < md[15]) {
        int ci = part_i[j*64 + t];
#pragma unroll
        for (int jj = 0; jj < 16; ++jj) {
          if (cd < md[jj]) { float td=md[jj]; int ti=mi[jj]; md[jj]=cd; mi[jj]=ci; cd=td; ci=ti; }
        }
      }
    }
    int* op = idx + (b*NN + q)*16;
#pragma unroll
    for (int j = 0; j < 16; ++j) op[j] = mi[j];
  }
}

// ---------------- x = relu(c @ w0[l] + b0[l]) ----------------
__global__ void xproj_kernel(const float* __restrict__ c,
                             const float* __restrict__ w0,
                             const float* __restrict__ b0,
                             float* __restrict__ x, int layer) {
  int tid = blockIdx.x * blockDim.x + threadIdx.x;
  if (tid >= NPTS*HH) return;
  int p = tid >> 5, h = tid & 31;
  const float* w = w0 + layer*DIMM*HH;
  const float* cr = c + p*DIMM;
  float acc = b0[layer*HH + h];
#pragma unroll
  for (int d = 0; d < DIMM; ++d) acc += cr[d]*w[d*HH + h];
  x[tid] = fmaxf(acc, 0.0f);
}

// ---------------- fused FKAConv v2: 256 thr = 4 waves = 4 points ----------------
// LDS layout (floats)
#define OFF_W1   0
#define OFF_W2AT 48        // [16][20] transposed fc2 rows 0..15  (w2aT[s][t]=fc2[t][s])
#define OFF_W2BT 368       // [16][20] transposed fc2 rows 16..31
#define OFF_W3AT 688
#define OFF_W3BT 1008
#define OFF_WL   1328      // w2 final proj [32][64]
#define OFF_B2   3376      // [64]
#define OFF_RED  3440      // y partials [8 seg][4 pt][32 o]
#define OFF_Y    4464      // [4 pt][32 o]
#define OFF_SCR  4592      // per-wave scratch x4
#define SCR_SZ   1808
#define S_DW 0             // [16]
#define S_M1 16            // [16][16]
#define S_M2 272
#define S_MM 528
#define S_XN 784           // [16][32]
#define S_FB 1296          // f [32 c][16 s]
#define LDS_TOT (OFF_SCR + 4*SCR_SZ)   // 11824 floats = 47296 B -> 3 blocks/CU

__global__ __launch_bounds__(256) void conv_kernel(
    float* __restrict__ c, const float* __restrict__ x,
    const int* __restrict__ idx, const float* __restrict__ xyz,
    const float* __restrict__ fc1, const float* __restrict__ fc2,
    const float* __restrict__ fc3, const float* __restrict__ wcv,
    const float* __restrict__ alpha, const float* __restrict__ beta,
    const float* __restrict__ w2, const float* __restrict__ b2, int layer)
{
  __shared__ __align__(16) float lds[LDS_TOT];
  int t = threadIdx.x;

  const float* fc1l = fc1 + layer*3*KK;
  const float* fc2l = fc2 + layer*2*KK*KK;
  const float* fc3l = fc3 + layer*2*KK*KK;
  const float* wcvl = wcv + layer*HH*HH*KK;
  const float* w2l  = w2  + layer*HH*DIMM;
  const float* b2l  = b2  + layer*DIMM;

  // ---- stage weights once per block ----
  if (t < 48) lds[OFF_W1 + t] = fc1l[t];
  {
    int s = t >> 4, tt = t & 15;
    lds[OFF_W2AT + s*20 + tt] = fc2l[tt*16 + s];
    lds[OFF_W2BT + s*20 + tt] = fc2l[(16+tt)*16 + s];
    lds[OFF_W3AT + s*20 + tt] = fc3l[tt*16 + s];
    lds[OFF_W3BT + s*20 + tt] = fc3l[(16+tt)*16 + s];
  }
#pragma unroll
  for (int r = 0; r < 8; ++r) lds[OFF_WL + t + 256*r] = w2l[t + 256*r];
  if (t < 64) lds[OFF_B2 + t] = b2l[t];
  __syncthreads();

  int wv = t >> 6, lane = t & 63;
  int p = blockIdx.x*4 + wv;          // global point
  int b = p >> 13;
  float* scr = lds + OFF_SCR + wv*SCR_SZ;
  int sI = lane & 15;

  // ---- group A: dw, xn gather, m1 ----
  float qxx = xyz[p*3+0], qyy = xyz[p*3+1], qzz = xyz[p*3+2];
  float alv = alpha[layer], bev = beta[layer];
  int jidx = 0; float px = 0, py = 0, pz = 0, sv = 0;
  if (lane < 16) {
    jidx = idx[p*16 + lane];
    const float* nb = xyz + ((long)b*NN + jidx)*3;
    px = nb[0]-qxx; py = nb[1]-qyy; pz = nb[2]-qzz;
    float dd = sqrtf(px*px + py*py + pz*pz + 1e-12f);
    sv = 1.0f/(1.0f + expf(alv*dd - bev));     // sigmoid(-a*d+b)
  }
  float ssum = 0.0f;                            // serial ascending-k sum (matches ref order)
#pragma unroll
  for (int k = 0; k < 16; ++k) ssum += __shfl(sv, k);
  if (lane < 16) scr[S_DW + lane] = sv / (ssum + 1e-6f) * 16.0f;
  // xn gather: 128 float4 tasks over 64 lanes x2
#pragma unroll
  for (int r = 0; r < 2; ++r) {
    int tsk = lane + 64*r;
    int k = tsk >> 3, seg = tsk & 7;
    int jk = __shfl(jidx, k);
    float4 v = *(const float4*)(x + ((long)b*NN + jk)*32 + seg*4);
    *(float4*)&scr[S_XN + k*32 + seg*4] = v;
  }
  // m1 = relu(pts @ fc1): pts via shuffle from lanes 0..15
#pragma unroll
  for (int r = 0; r < 4; ++r) {
    int k = (lane >> 4) + 4*r;
    float pxk = __shfl(px, k), pyk = __shfl(py, k), pzk = __shfl(pz, k);
    float v = pxk*lds[OFF_W1+sI] + pyk*lds[OFF_W1+16+sI] + pzk*lds[OFF_W1+32+sI];
    scr[S_M1 + k*16 + sI] = fmaxf(v, 0.0f);
  }
  __syncthreads();

  // ---- group B: mp1, q1 (shuffle), m2 ----
  {
    float mpv = 0.0f;
#pragma unroll
    for (int k = 0; k < 16; ++k) mpv = fmaxf(mpv, scr[S_M1 + k*16 + sI] * scr[S_DW + k]);
    float qv = 0.0f;
#pragma unroll
    for (int tt = 0; tt < 16; ++tt) qv += __shfl(mpv, tt) * lds[OFF_W2BT + sI*20 + tt];
    float4 wa0 = *(float4*)&lds[OFF_W2AT + sI*20 + 0];
    float4 wa1 = *(float4*)&lds[OFF_W2AT + sI*20 + 4];
    float4 wa2 = *(float4*)&lds[OFF_W2AT + sI*20 + 8];
    float4 wa3 = *(float4*)&lds[OFF_W2AT + sI*20 + 12];
#pragma unroll
    for (int r = 0; r < 4; ++r) {
      int k = (lane >> 4) + 4*r;
      float4 m0 = *(float4*)&scr[S_M1 + k*16 + 0];
      float4 m1_ = *(float4*)&scr[S_M1 + k*16 + 4];
      float4 m2_ = *(float4*)&scr[S_M1 + k*16 + 8];
      float4 m3_ = *(float4*)&scr[S_M1 + k*16 + 12];
      float v = qv;
      v += m0.x*wa0.x; v += m0.y*wa0.y; v += m0.z*wa0.z; v += m0.w*wa0.w;
      v += m1_.x*wa1.x; v += m1_.y*wa1.y; v += m1_.z*wa1.z; v += m1_.w*wa1.w;
      v += m2_.x*wa2.x; v += m2_.y*wa2.y; v += m2_.z*wa2.z; v += m2_.w*wa2.w;
      v += m3_.x*wa3.x; v += m3_.y*wa3.y; v += m3_.z*wa3.z; v += m3_.w*wa3.w;
      scr[S_M2 + k*16 + sI] = fmaxf(v, 0.0f);
    }
  }
  __syncthreads();

  // ---- group C: mp2, q2, m3 -> mm = relu(.)*dw ----
  {
    float mpv = 0.0f;
#pragma unroll
    for (int k = 0; k < 16; ++k) mpv = fmaxf(mpv, scr[S_M2 + k*16 + sI] * scr[S_DW + k]);
    float qv = 0.0f;
#pragma unroll
    for (int tt = 0; tt < 16; ++tt) qv += __shfl(mpv, tt) * lds[OFF_W3BT + sI*20 + tt];
    float4 wa0 = *(float4*)&lds[OFF_W3AT + sI*20 + 0];
    float4 wa1 = *(float4*)&lds[OFF_W3AT + sI*20 + 4];
    float4 wa2 = *(float4*)&lds[OFF_W3AT + sI*20 + 8];
    float4 wa3 = *(float4*)&lds[OFF_W3AT + sI*20 + 12];
#pragma unroll
    for (int r = 0; r < 4; ++r) {
      int k = (lane >> 4) + 4*r;
      float4 m0 = *(float4*)&scr[S_M2 + k*16 + 0];
      float4 m1_ = *(float4*)&scr[S_M2 + k*16 + 4];
      float4 m2_ = *(float4*)&scr[S_M2 + k*16 + 8];
      float4 m3_ = *(float4*)&scr[S_M2 + k*16 + 12];
      float v = qv;
      v += m0.x*wa0.x; v += m0.y*wa0.y; v += m0.z*wa0.z; v += m0.w*wa0.w;
      v += m1_.x*wa1.x; v += m1_.y*wa1.y; v += m1_.z*wa1.z; v += m1_.w*wa1.w;
      v += m2_.x*wa2.x; v += m2_.y*wa2.y; v += m2_.z*wa2.z; v += m2_.w*wa2.w;
      v += m3_.x*wa3.x; v += m3_.y*wa3.y; v += m3_.z*wa3.z; v += m3_.w*wa3.w;
      scr[S_MM + k*16 + sI] = fmaxf(v, 0.0f) * scr[S_DW + k];
    }
  }
  __syncthreads();

  // ---- group D: f[c][s] = sum_k xn[k][c]*mm[k][s], 8 c-values per lane in regs ----
  {
    int q4 = lane >> 4;
    float fr0=0,fr1=0,fr2=0,fr3=0,fr4=0,fr5=0,fr6=0,fr7=0;
#pragma unroll
    for (int k = 0; k < 16; ++k) {
      float mmv = scr[S_MM + k*16 + sI];
      float4 a  = *(float4*)&scr[S_XN + k*32 + q4*8];
      float4 bb = *(float4*)&scr[S_XN + k*32 + q4*8 + 4];
      fr0 += a.x*mmv;  fr1 += a.y*mmv;  fr2 += a.z*mmv;  fr3 += a.w*mmv;
      fr4 += bb.x*mmv; fr5 += bb.y*mmv; fr6 += bb.z*mmv; fr7 += bb.w*mmv;
    }
    scr[S_FB + (q4*8+0)*16 + sI] = fr0;
    scr[S_FB + (q4*8+1)*16 + sI] = fr1;
    scr[S_FB + (q4*8+2)*16 + sI] = fr2;
    scr[S_FB + (q4*8+3)*16 + sI] = fr3;
    scr[S_FB + (q4*8+4)*16 + sI] = fr4;
    scr[S_FB + (q4*8+5)*16 + sI] = fr5;
    scr[S_FB + (q4*8+6)*16 + sI] = fr6;
    scr[S_FB + (q4*8+7)*16 + sI] = fr7;
  }
  __syncthreads();

  // ---- block GEMM y-einsum: thread (o, seg): wcv read ONCE per block ----
  {
    int o = t & 31, seg = t >> 5;          // 8 segs x 64 cs
    const float4* wrow = (const float4*)(wcvl + o*512 + seg*64);
    float acc0=0, acc1=0, acc2=0, acc3=0;
#pragma unroll
    for (int j = 0; j < 16; ++j) {
      float4 w4 = wrow[j];
      float4 f0 = *(const float4*)&lds[OFF_SCR + 0*SCR_SZ + S_FB + seg*64 + j*4];
      float4 f1 = *(const float4*)&lds[OFF_SCR + 1*SCR_SZ + S_FB + seg*64 + j*4];
      float4 f2 = *(const float4*)&lds[OFF_SCR + 2*SCR_SZ + S_FB + seg*64 + j*4];
      float4 f3 = *(const float4*)&lds[OFF_SCR + 3*SCR_SZ + S_FB + seg*64 + j*4];
      acc0 += w4.x*f0.x; acc0 += w4.y*f0.y; acc0 += w4.z*f0.z; acc0 += w4.w*f0.w;
      acc1 += w4.x*f1.x; acc1 += w4.y*f1.y; acc1 += w4.z*f1.z; acc1 += w4.w*f1.w;
      acc2 += w4.x*f2.x; acc2 += w4.y*f2.y; acc2 += w4.z*f2.z; acc2 += w4.w*f2.w;
      acc3 += w4.x*f3.x; acc3 += w4.y*f3.y; acc3 += w4.z*f3.z; acc3 += w4.w*f3.w;
    }
    lds[OFF_RED + seg*128 + 0*32 + o] = acc0;
    lds[OFF_RED + seg*128 + 1*32 + o] = acc1;
    lds[OFF_RED + seg*128 + 2*32 + o] = acc2;
    lds[OFF_RED + seg*128 + 3*32 + o] = acc3;
  }
  __syncthreads();

  // ---- reduce segs + relu ----
  if (t < 128) {
    int pt = t >> 5, o = t & 31;
    float yv = 0.0f;
#pragma unroll
    for (int seg = 0; seg < 8; ++seg) yv += lds[OFF_RED + seg*128 + pt*32 + o];
    lds[OFF_Y + pt*32 + o] = fmaxf(yv, 0.0f);
  }
  __syncthreads();

  // ---- final: c = relu(y @ w2 + b2 + c), 1 output/thread ----
  {
    int pt = t >> 6, d = t & 63;
    float zv = lds[OFF_B2 + d];
#pragma unroll
    for (int o = 0; o < 32; ++o) zv += lds[OFF_Y + pt*32 + o] * lds[OFF_WL + o*64 + d];
    int gp = blockIdx.x*4 + pt;
    float cv = c[gp*64 + d];
    c[gp*64 + d] = fmaxf(zv + cv, 0.0f);
  }
}

// ---------------- triplane scatter-accumulate ----------------
__global__ void triacc_kernel(const float* __restrict__ c,
                              const float* __restrict__ xyz,
                              float* __restrict__ psum,
                              float* __restrict__ pcnt) {
  int tid = blockIdx.x * blockDim.x + threadIdx.x;
  if (tid >= NPTS*DIMM) return;
  int p = tid >> 6, d = tid & 63;
  int b = p >> 13;
  float p0 = xyz[p*3+0] / 1.101f + 0.5f;
  float p1 = xyz[p*3+1] / 1.101f + 0.5f;
  float p2 = xyz[p*3+2] / 1.101f + 0.5f;
  int i0 = min(max((int)(p0*64.0f), 0), 63);
  int i1 = min(max((int)(p1*64.0f), 0), 63);
  int i2 = min(max((int)(p2*64.0f), 0), 63);
  int cb = b*3*RESS*RESS;
  int c0 = cb + 0*RESS*RESS + i0*RESS + i1;   // xy plane
  int c1 = cb + 1*RESS*RESS + i0*RESS + i2;   // xz plane
  int c2 = cb + 2*RESS*RESS + i1*RESS + i2;   // yz plane
  float v = c[tid];
  atomicAdd(&psum[c0*DIMM + d], v);
  atomicAdd(&psum[c1*DIMM + d], v);
  atomicAdd(&psum[c2*DIMM + d], v);
  if (d == 0) {
    atomicAdd(&pcnt[c0], 1.0f);
    atomicAdd(&pcnt[c1], 1.0f);
    atomicAdd(&pcnt[c2], 1.0f);
  }
}

// ---------------- triplane normalize ----------------
__global__ void trinorm_kernel(const float* __restrict__ psum,
                               const float* __restrict__ pcnt,
                               float* __restrict__ out) {
  int tid = blockIdx.x * blockDim.x + threadIdx.x;
  if (tid >= PLANE_ELEMS) return;
  float cnt = pcnt[tid >> 6];
  out[tid] = psum[tid] / fmaxf(cnt, 1.0f);
}

extern "C" void kernel_launch(void* const* d_in, const int* in_sizes, int n_in,
                              void* d_out, int out_size, void* d_ws, size_t ws_size,
                              hipStream_t stream) {
  const float* xyz   = (const float*)d_in[0];
  const float* wstem = (const float*)d_in[1];
  const float* bstem = (const float*)d_in[2];
  const float* w0    = (const float*)d_in[3];
  const float* b0    = (const float*)d_in[4];
  const float* fc1   = (const float*)d_in[5];
  const float* fc2   = (const float*)d_in[6];
  const float* fc3   = (const float*)d_in[7];
  const float* wcv   = (const float*)d_in[8];
  const float* alpha = (const float*)d_in[9];
  const float* beta  = (const float*)d_in[10];
  const float* w2    = (const float*)d_in[11];
  const float* b2    = (const float*)d_in[12];

  float* out     = (float*)d_out;
  float* out_xyz = out;                       // 49152
  float* c       = out + NPTS*3;              // working c buffer
  float* out_tri = c + NPTS*DIMM;             // 1572864

  float* wsf  = (float*)d_ws;
  int*   idx  = (int*)d_ws;                   // NPTS*16 int32
  float* x    = wsf + NPTS*16;                // NPTS*32
  float* psum = x + NPTS*HH;                  // PLANE_ELEMS
  float* pcnt = psum + PLANE_ELEMS;           // PLANE_CELLS

  int nz = PLANE_ELEMS + PLANE_CELLS;
  zero_kernel<<<(nz+255)/256, 256, 0, stream>>>(psum, nz);
  stem_kernel<<<(NPTS*DIMM+255)/256, 256, 0, stream>>>(xyz, wstem, bstem, out_xyz, c);
  knn_kernel<<<256, 512, 0, stream>>>(xyz, idx);
  for (int layer = 0; layer < NBB; ++layer) {
    xproj_kernel<<<(NPTS*HH+255)/256, 256, 0, stream>>>(c, w0, b0, x, layer);
    conv_kernel<<<NPTS/4, 256, 0, stream>>>(c, x, idx, xyz, fc1, fc2, fc3, wcv,
                                            alpha, beta, w2, b2, layer);
  }
  triacc_kernel<<<(NPTS*DIMM+255)/256, 256, 0, stream>>>(c, xyz, psum, pcnt);
  trinorm_kernel<<<(PLANE_ELEMS+255)/256, 256, 0, stream>>>(psum, pcnt, out_tri);
}